// Round 19
// baseline (158.589 us; speedup 1.0000x reference)
//
#include <hip/hip_runtime.h>
#include <cstdint>
#include <cstddef>

typedef unsigned short u16;
typedef __bf16 bf16;
typedef bf16 __attribute__((ext_vector_type(2))) bf16x2;
typedef bf16 __attribute__((ext_vector_type(8))) bf16x8;
typedef float __attribute__((ext_vector_type(4))) f32x4;
typedef u16 __attribute__((ext_vector_type(8))) u16x8;

// SCALE * log2(e) folded into Q so softmax runs in exp2 domain
#define QSCALE 0.18033688011112042f

__device__ __forceinline__ u16 f2b(float x) {
  unsigned u = __float_as_uint(x);
  unsigned r = (u + 0x7fffu + ((u >> 16) & 1u)) >> 16;   // RNE
  return (u16)r;
}

__device__ __forceinline__ void gl_lds16(const void* g, void* lds) {
  __builtin_amdgcn_global_load_lds(
      (const __attribute__((address_space(1))) unsigned int*)g,
      (__attribute__((address_space(3))) unsigned int*)lds, 16, 0, 0);
}

// ---- BK=64 tiles ([rows][64], (row&7) chunk-XOR swizzle) --------------------
__device__ __forceinline__ bf16x8 frag(const u16* base, int row, int kchunk) {
  const int c = kchunk ^ (row & 7);
  return *(const bf16x8*)(base + row * 64 + c * 8);
}
__device__ __forceinline__ void stage_tile4(const u16* gbase, int K, char* lbase,
                                            int wave, int lane) {
#pragma unroll
  for (int i = 0; i < 4; ++i) {
    const int q = wave * 64 + lane + i * 256;
    const int r = q >> 3, c = (q & 7) ^ (r & 7);
    gl_lds16(gbase + (size_t)r * K + c * 8, lbase + i * 4096 + wave * 1024);
  }
}

// ---- BK=32 tiles ([rows][32], ((row>>1)&3) chunk-XOR swizzle; 2-way = free) -
__device__ __forceinline__ bf16x8 frag32(const u16* base, int row, int kchunk) {
  const int c = kchunk ^ ((row >> 1) & 3);
  return *(const bf16x8*)(base + row * 32 + c * 8);
}

// ---------------- merged cast fp32 -> bf16 (x, w_qkv, w_out in one launch) ---
__global__ __launch_bounds__(256) void castk3(const float* __restrict__ x,
                                              const float* __restrict__ wq,
                                              const float* __restrict__ wo,
                                              u16* __restrict__ xb,
                                              u16* __restrict__ wqb,
                                              u16* __restrict__ wob) {
  const int blk = blockIdx.x;
  const float* in;
  u16* out;
  int base;
  if (blk < 4096)      { in = x;  out = xb;  base = blk; }
  else if (blk < 5632) { in = wq; out = wqb; base = blk - 4096; }
  else                 { in = wo; out = wob; base = blk - 5632; }
  const int i = (base * 256 + threadIdx.x) * 8;
  float4 a = *(const float4*)(in + i);
  float4 b = *(const float4*)(in + i + 4);
  u16x8 v;
  v[0] = f2b(a.x); v[1] = f2b(a.y); v[2] = f2b(a.z); v[3] = f2b(a.w);
  v[4] = f2b(b.x); v[5] = f2b(b.y); v[6] = f2b(b.z); v[7] = f2b(b.w);
  *(u16x8*)(out + i) = v;
}

// ---------------- GEMM1: 256x128 tile, 256 thr, BK=32, dbuf (FROZEN) ---------
// Pinned at ~79 us across dbuf/tribuf/128^2/256x128 = the 2-phase-loop
// structure ceiling at K=1024 (matches m248's 655 TF); geometry blocks the
// 8-phase escape (384 tiles on 256 CUs). Frozen.
__global__ __launch_bounds__(256, 3) void gemm_qkv(
    const u16* __restrict__ A, const u16* __restrict__ B,
    u16* __restrict__ Qo, u16* __restrict__ Ko, u16* __restrict__ Vo) {
  __shared__ u16 As[2][256 * 32];   // 16KB per buf
  __shared__ u16 Bs[2][128 * 32];   // 8KB per buf
  const int tid = threadIdx.x;
  const int lane = tid & 63, wave = tid >> 6;
  const int fr = lane & 15, fg = lane >> 4;
  const int wm = wave >> 1, wn = wave & 1;
  const int bid = blockIdx.x;
  const int bm = bid & 31, bn = bid >> 5;   // 32 x 24 grid
  const int K = 1024;
  const u16* Ab = A + (size_t)bm * 256 * K;
  const u16* Bb = B + (size_t)bn * 128 * K;

  f32x4 acc[8][4] = {};

  auto stageA = [&](const u16* gbase, char* lbase) {
#pragma unroll
    for (int i = 0; i < 4; ++i) {
      const int q = wave * 64 + lane + i * 256;
      const int r = q >> 2, c = (q & 3) ^ ((r >> 1) & 3);
      gl_lds16(gbase + (size_t)r * K + c * 8, lbase + i * 4096 + wave * 1024);
    }
  };
  auto stageB = [&](const u16* gbase, char* lbase) {
#pragma unroll
    for (int i = 0; i < 2; ++i) {
      const int q = wave * 64 + lane + i * 256;
      const int r = q >> 2, c = (q & 3) ^ ((r >> 1) & 3);
      gl_lds16(gbase + (size_t)r * K + c * 8, lbase + i * 4096 + wave * 1024);
    }
  };

  stageA(Ab, (char*)&As[0][0]);
  stageB(Bb, (char*)&Bs[0][0]);
  __syncthreads();

  int cur = 0;
#pragma unroll 1
  for (int t = 0; t < 32; ++t) {
    if (t < 31) {
      stageA(Ab + (size_t)(t + 1) * 32, (char*)&As[cur ^ 1][0]);
      stageB(Bb + (size_t)(t + 1) * 32, (char*)&Bs[cur ^ 1][0]);
    }
    bf16x8 bfv[4];
#pragma unroll
    for (int ni = 0; ni < 4; ++ni)
      bfv[ni] = frag32(&Bs[cur][0], wn * 64 + ni * 16 + fr, fg);
#pragma unroll
    for (int mi = 0; mi < 8; ++mi) {
      const bf16x8 af = frag32(&As[cur][0], wm * 128 + mi * 16 + fr, fg);
#pragma unroll
      for (int ni = 0; ni < 4; ++ni)
        acc[mi][ni] = __builtin_amdgcn_mfma_f32_16x16x32_bf16(
            af, bfv[ni], acc[mi][ni], 0, 0, 0);
    }
    __syncthreads();
    cur ^= 1;
  }

  const int gr0 = bm * 256 + wm * 128;
  const int gc0 = bn * 128 + wn * 64;
#pragma unroll
  for (int mi = 0; mi < 8; ++mi) {
    const int rb = gr0 + mi * 16 + fg * 4;
    const int b = rb >> 10, t = rb & 1023;
#pragma unroll
    for (int ni = 0; ni < 4; ++ni) {
      const int c = gc0 + ni * 16 + fr;
      const int region = c >> 10, cc = c & 1023;
      const int h = cc >> 6, d = cc & 63;
      const size_t bh = (size_t)(b * 16 + h);
      if (region == 0) {
#pragma unroll
        for (int g = 0; g < 4; ++g)
          Qo[(bh * 1024 + t + g) * 64 + d] = f2b(acc[mi][ni][g] * QSCALE);
      } else if (region == 1) {
#pragma unroll
        for (int g = 0; g < 4; ++g)
          Ko[(bh * 1024 + t + g) * 64 + d] = f2b(acc[mi][ni][g]);
      } else {
        ushort4 pv;
        pv.x = f2b(acc[mi][ni][0]);
        pv.y = f2b(acc[mi][ni][1]);
        pv.z = f2b(acc[mi][ni][2]);
        pv.w = f2b(acc[mi][ni][3]);
        *(ushort4*)(Vo + (bh * 64 + d) * 1024 + t) = pv;   // V^T: [bh][d][t]
      }
    }
  }
}

// ---------------- GEMM2: 128x128, BK=64, dbuf, 1 sync/iter, swizzled --------
__global__ __launch_bounds__(256) void gemm_bt2(
    const u16* __restrict__ A, const u16* __restrict__ B,
    float* __restrict__ Co, const float* __restrict__ bias,
    const float* __restrict__ msk) {
  __shared__ u16 As[2][128 * 64];
  __shared__ u16 Bs[2][128 * 64];
  const int tid = threadIdx.x;
  const int lane = tid & 63, wave = tid >> 6;
  const int fr = lane & 15, fg = lane >> 4;
  const int wr = wave >> 1, wc = wave & 1;
  const int bid = blockIdx.x;
  const int bm = bid & 63, bn = bid >> 6;
  const int K = 1024, N = 1024;
  const u16* Ab = A + (size_t)bm * 128 * K;
  const u16* Bb = B + (size_t)bn * 128 * K;

  f32x4 acc[4][4] = {};

  stage_tile4(Ab, K, (char*)&As[0][0], wave, lane);
  stage_tile4(Bb, K, (char*)&Bs[0][0], wave, lane);
  __syncthreads();

  int cur = 0;
#pragma unroll 1
  for (int t = 0; t < 16; ++t) {
    if (t < 15) {
      stage_tile4(Ab + (size_t)(t + 1) * 64, K, (char*)&As[cur ^ 1][0], wave, lane);
      stage_tile4(Bb + (size_t)(t + 1) * 64, K, (char*)&Bs[cur ^ 1][0], wave, lane);
    }
    bf16x8 af[4][2], bfv[4][2];
#pragma unroll
    for (int mi = 0; mi < 4; ++mi)
#pragma unroll
      for (int kk = 0; kk < 2; ++kk)
        af[mi][kk] = frag(&As[cur][0], wr * 64 + mi * 16 + fr, kk * 4 + fg);
#pragma unroll
    for (int ni = 0; ni < 4; ++ni)
#pragma unroll
      for (int kk = 0; kk < 2; ++kk)
        bfv[ni][kk] = frag(&Bs[cur][0], wc * 64 + ni * 16 + fr, kk * 4 + fg);
#pragma unroll
    for (int mi = 0; mi < 4; ++mi)
#pragma unroll
      for (int ni = 0; ni < 4; ++ni)
#pragma unroll
        for (int kk = 0; kk < 2; ++kk)
          acc[mi][ni] = __builtin_amdgcn_mfma_f32_16x16x32_bf16(
              af[mi][kk], bfv[ni][kk], acc[mi][ni], 0, 0, 0);
    __syncthreads();
    cur ^= 1;
  }

  const int gr0 = bm * 128 + wr * 64;
  const int gc0 = bn * 128 + wc * 64;
#pragma unroll
  for (int mi = 0; mi < 4; ++mi) {
    const int rb = gr0 + mi * 16 + fg * 4;
#pragma unroll
    for (int ni = 0; ni < 4; ++ni) {
      const int c = gc0 + ni * 16 + fr;
      const float bo = bias[c];
#pragma unroll
      for (int g = 0; g < 4; ++g) {
        const int r = rb + g;
        Co[(size_t)r * N + c] = (acc[mi][ni][g] + bo) * msk[r];
      }
    }
  }
}

// ---------------- causal flash attention: 64-row strips, staged K/V ---------
// LDS diet: exactly 32KB (K/V dbuf only) -> up to 5 blocks/CU. Mask handling
// moved fully out of LDS: all-ones detection per-wave in registers (once,
// before the loop); rare non-trivial path reads msk float4s from global.
__global__ __launch_bounds__(256) void attnk(const u16* __restrict__ Qb,
                                             const u16* __restrict__ Kb,
                                             const u16* __restrict__ Vtb,
                                             const float* __restrict__ msk,
                                             u16* __restrict__ Ob) {
  __shared__ u16 Ks[2][64 * 64];     // [buf][t][d], swizzled via staged source
  __shared__ u16 Vs[2][64 * 64];     // [buf][d][t], swizzled via staged source
  const int tid = threadIdx.x;
  const int lane = tid & 63, wave = tid >> 6;
  const int fr = lane & 15, fg = lane >> 4;
  const int bid = blockIdx.x;
  const int s = bid >> 7;            // pair index 0..7
  const int bh = bid & 127;
  const int b = bh >> 4, h = bh & 15;
  const float* mrow = msk + (size_t)b * 1024;

  // per-wave all-ones mask detection (no LDS, no barrier, loop-invariant)
  bool aok = true;
#pragma unroll
  for (int i = 0; i < 4; ++i) {
    const float4 mv = ((const float4*)mrow)[lane * 4 + i];
    aok = aok && (mv.x == 1.f) && (mv.y == 1.f) && (mv.z == 1.f) && (mv.w == 1.f);
  }
  const bool mfast = __all((int)aok);

  auto stage = [&](int kb, int buf) {
    const int q0 = wave * 64 + lane;
    const int r0 = q0 >> 3, c0 = (q0 & 7) ^ (r0 & 7);
    gl_lds16(Kb + ((size_t)bh * 1024 + kb * 64 + r0) * 64 + c0 * 8,
             (char*)&Ks[buf][0] + wave * 1024);
    gl_lds16(Vtb + ((size_t)bh * 64 + r0) * 1024 + kb * 64 + c0 * 8,
             (char*)&Vs[buf][0] + wave * 1024);
    const int q1 = q0 + 256;
    const int r1 = q1 >> 3, c1 = (q1 & 7) ^ (r1 & 7);
    gl_lds16(Kb + ((size_t)bh * 1024 + kb * 64 + r1) * 64 + c1 * 8,
             (char*)&Ks[buf][0] + 4096 + wave * 1024);
    gl_lds16(Vtb + ((size_t)bh * 64 + r1) * 1024 + kb * 64 + c1 * 8,
             (char*)&Vs[buf][0] + 4096 + wave * 1024);
  };

  int qw = s * 64 + wave * 16;       // wave's 16 q-rows
  bf16x8 qf[2];
  auto loadQ = [&]() {
#pragma unroll
    for (int kc = 0; kc < 2; ++kc)
      qf[kc] = *(const bf16x8*)(Qb + ((size_t)bh * 1024 + qw + fr) * 64 +
                                kc * 32 + fg * 8);
  };
  loadQ();

  f32x4 o[4] = {};
  float mrun = -3.0e38f, lrun = 0.f;

  auto writeO = [&]() {
    const float inv = 1.0f / lrun;
#pragma unroll
    for (int g = 0; g < 4; ++g) {
      const float invr = __shfl(inv, fg * 4 + g);
      const int q = qw + fg * 4 + g;
#pragma unroll
      for (int dt = 0; dt < 4; ++dt)
        Ob[((size_t)b * 1024 + q) * 1024 + h * 64 + dt * 16 + fr] =
            f2b(o[dt][g] * invr);
    }
  };

  stage(0, 0);   // prologue: strip A, kb=0

#pragma unroll 1
  for (int it = 0; it <= 16; ++it) {   // 17 subs, uniform for every block
    __syncthreads();                   // stage(it) landed (implicit vmcnt0)
    if (it < 16) {                     // prefetch next sub; hides under compute
      const int nkb = (it + 1 <= s) ? (it + 1) : (it - s);
      stage(nkb, (it + 1) & 1);
    }
    if (it == s + 1) {                 // switch strip A -> strip B
      writeO();
      qw = (15 - s) * 64 + wave * 16;
      loadQ();
#pragma unroll
      for (int dt = 0; dt < 4; ++dt) o[dt] = f32x4{0.f, 0.f, 0.f, 0.f};
      mrun = -3.0e38f;
      lrun = 0.f;
    }
    const int kb = (it <= s) ? it : (it - s - 1);
    const u16* Kc = &Ks[it & 1][0];
    const u16* Vc = &Vs[it & 1][0];

    // --- S^T = K * Q^T : lane owns q-row = qw+fr, k = nt*16 + fg*4 + g ---
    f32x4 st[4];
    const f32x4 z = {0.f, 0.f, 0.f, 0.f};
    bf16x8 kf0[4], kf1[4];
#pragma unroll
    for (int nt = 0; nt < 4; ++nt) {
      const int krow = nt * 16 + fr;
      const int cb0r = (0 * 4 + fg) ^ (krow & 7);
      const int cb1r = (1 * 4 + fg) ^ (krow & 7);
      kf0[nt] = *(const bf16x8*)(Kc + krow * 64 + cb0r * 8);
      kf1[nt] = *(const bf16x8*)(Kc + krow * 64 + cb1r * 8);
    }
    __builtin_amdgcn_s_setprio(1);
#pragma unroll
    for (int nt = 0; nt < 4; ++nt) {
      st[nt] = __builtin_amdgcn_mfma_f32_16x16x32_bf16(kf0[nt], qf[0], z, 0, 0, 0);
      st[nt] = __builtin_amdgcn_mfma_f32_16x16x32_bf16(kf1[nt], qf[1], st[nt], 0, 0, 0);
    }
    __builtin_amdgcn_s_setprio(0);

    // --- causal mask: needed unless ALL keys <= MIN q-row of the wave (qw) ---
    if (kb * 64 + 63 > qw) {
      const int q = qw + fr;
#pragma unroll
      for (int nt = 0; nt < 4; ++nt)
#pragma unroll
        for (int g = 0; g < 4; ++g) {
          const int j = kb * 64 + nt * 16 + fg * 4 + g;
          if (j > q) st[nt][g] = -3.0e38f;
        }
    }

    // --- online softmax with defer-max (T13, THR=8) ---
    float mxl = st[0][0];
#pragma unroll
    for (int nt = 0; nt < 4; ++nt)
#pragma unroll
      for (int g = 0; g < 4; ++g) mxl = fmaxf(mxl, st[nt][g]);
    float nm, sc;
    int doR;
    if (__all(mxl <= mrun + 8.f)) {
      nm = mrun; sc = 1.f; doR = 0;
    } else {
      float mx = fmaxf(mxl, __shfl_xor(mxl, 16));
      mx = fmaxf(mx, __shfl_xor(mx, 32));
      nm = fmaxf(mrun, mx);
      sc = exp2f(mrun - nm);
      mrun = nm; doR = 1;
    }
    float rs = 0.f;
    if (mfast) {                       // trivial padding mask: no mask work
#pragma unroll
      for (int nt = 0; nt < 4; ++nt)
#pragma unroll
        for (int g = 0; g < 4; ++g) {
          const float pq = exp2f(st[nt][g] - nm);
          st[nt][g] = pq;
          rs += pq;
        }
    } else {                           // rare: read mask from global (L2-hot)
      float kmv[4][4];
#pragma unroll
      for (int nt = 0; nt < 4; ++nt) {
        const float4 km4 = *(const float4*)(mrow + kb * 64 + nt * 16 + fg * 4);
        kmv[nt][0] = km4.x; kmv[nt][1] = km4.y; kmv[nt][2] = km4.z; kmv[nt][3] = km4.w;
      }
#pragma unroll
      for (int nt = 0; nt < 4; ++nt)
#pragma unroll
        for (int g = 0; g < 4; ++g) {
          const float pq = exp2f(st[nt][g] - nm) * kmv[nt][g];
          st[nt][g] = pq;
          rs += pq;
        }
    }
    rs += __shfl_xor(rs, 16);
    rs += __shfl_xor(rs, 32);
    lrun = doR ? (lrun * sc + rs) : (lrun + rs);

    // --- pack P pairs to bf16x2 words (v_cvt_pk_bf16_f32) ---
    int pk[4][2];
#pragma unroll
    for (int nt = 0; nt < 4; ++nt)
#pragma unroll
      for (int hh = 0; hh < 2; ++hh) {
        bf16x2 tp;
        tp[0] = (bf16)st[nt][2 * hh];
        tp[1] = (bf16)st[nt][2 * hh + 1];
        pk[nt][hh] = __builtin_bit_cast(int, tp);
      }

    // --- redistribute to PV A-fragments via shfl (wave-uniform reg indices,
    //     per-lane select; lane-varying index inside __shfl was the r8 bug) ---
    bf16x8 pa[2];
#pragma unroll
    for (int jc = 0; jc < 2; ++jc) {
      int w[4];
#pragma unroll
      for (int e2 = 0; e2 < 4; ++e2) {
        const int sl = fr + ((fg & 1) << 5) + ((e2 & 2) ? 16 : 0);
        const int lo = __shfl(pk[jc * 2 + 0][e2 & 1], sl);
        const int hi = __shfl(pk[jc * 2 + 1][e2 & 1], sl);
        w[e2] = (fg & 2) ? hi : lo;
      }
      int4 wi = {w[0], w[1], w[2], w[3]};
      pa[jc] = __builtin_bit_cast(bf16x8, wi);
    }

    // --- rescale O only when max grew (wave-uniform branch) ---
    if (doR) {
#pragma unroll
      for (int g = 0; g < 4; ++g) {
        const float scr = __shfl(sc, fg * 4 + g);
#pragma unroll
        for (int dt = 0; dt < 4; ++dt) o[dt][g] *= scr;
      }
    }

    // --- PV: O[q][d] += P[q][k] * V[k][d] ---
    __builtin_amdgcn_s_setprio(1);
#pragma unroll
    for (int jc = 0; jc < 2; ++jc)
#pragma unroll
      for (int dt = 0; dt < 4; ++dt) {
        const int vrow = dt * 16 + fr;
        const int cb = (jc * 4 + fg) ^ (vrow & 7);
        const bf16x8 vf = *(const bf16x8*)(Vc + vrow * 64 + cb * 8);
        o[dt] = __builtin_amdgcn_mfma_f32_16x16x32_bf16(pa[jc], vf, o[dt], 0, 0, 0);
      }
    __builtin_amdgcn_s_setprio(0);
  }

  writeO();   // strip B epilogue
}

// ---------------- launcher ----------------
extern "C" void kernel_launch(void* const* d_in, const int* in_sizes, int n_in,
                              void* d_out, int out_size, void* d_ws, size_t ws_size,
                              hipStream_t stream) {
  (void)in_sizes; (void)n_in; (void)out_size; (void)ws_size;
  const float* x = (const float*)d_in[0];
  const float* m = (const float*)d_in[1];
  const float* w_qkv = (const float*)d_in[2];
  const float* w_out = (const float*)d_in[3];
  const float* b_out = (const float*)d_in[4];
  float* out = (float*)d_out;

  char* ws = (char*)d_ws;
  const size_t MB = 1u << 20;
  u16* Xb    = (u16*)(ws + 0);         // 16MB, reused as Ob after GEMM1
  u16* Wqkvb = (u16*)(ws + 16 * MB);   // 6MB
  u16* Woutb = (u16*)(ws + 22 * MB);   // 2MB
  u16* Qb    = (u16*)(ws + 24 * MB);   // 16MB
  u16* Kb    = (u16*)(ws + 40 * MB);   // 16MB
  u16* Vtb   = (u16*)(ws + 56 * MB);   // 16MB  -> total 72MB
  u16* Ob    = Xb;                      // alias: X dead after GEMM1

  // merged casts (one launch: x, w_qkv, w_out)
  castk3<<<6144, 256, 0, stream>>>(x, w_qkv, w_out, Xb, Wqkvb, Woutb);

  // GEMM1: qkv = X @ Wqkv^T (256x128 tile, 256 thr, BK=32 dbuf, 3 blocks/CU)
  gemm_qkv<<<768, 256, 0, stream>>>(Xb, Wqkvb, Qb, Kb, Vtb);

  // flash attention (64-row strips paired, 32KB LDS, mask out of LDS)
  attnk<<<1024, 256, 0, stream>>>(Qb, Kb, Vtb, m, Ob);

  // GEMM2: out = (O @ Wout^T + b_out) * m  (128^2, BK=64 dbuf)
  gemm_bt2<<<512, 256, 0, stream>>>(Ob, Woutb, out, b_out, m);
}

// Round 20
// 146.732 us; speedup vs baseline: 1.0808x; 1.0808x over previous
//
#include <hip/hip_runtime.h>
#include <cstdint>
#include <cstddef>

typedef unsigned short u16;
typedef __bf16 bf16;
typedef bf16 __attribute__((ext_vector_type(2))) bf16x2;
typedef bf16 __attribute__((ext_vector_type(8))) bf16x8;
typedef float __attribute__((ext_vector_type(4))) f32x4;
typedef u16 __attribute__((ext_vector_type(8))) u16x8;

// SCALE * log2(e) folded into Q so softmax runs in exp2 domain
#define QSCALE 0.18033688011112042f

__device__ __forceinline__ u16 f2b(float x) {
  unsigned u = __float_as_uint(x);
  unsigned r = (u + 0x7fffu + ((u >> 16) & 1u)) >> 16;   // RNE
  return (u16)r;
}

__device__ __forceinline__ void gl_lds16(const void* g, void* lds) {
  __builtin_amdgcn_global_load_lds(
      (const __attribute__((address_space(1))) unsigned int*)g,
      (__attribute__((address_space(3))) unsigned int*)lds, 16, 0, 0);
}

// ---- BK=64 tiles ([rows][64], (row&7) chunk-XOR swizzle) --------------------
__device__ __forceinline__ bf16x8 frag(const u16* base, int row, int kchunk) {
  const int c = kchunk ^ (row & 7);
  return *(const bf16x8*)(base + row * 64 + c * 8);
}
__device__ __forceinline__ void stage_tile4(const u16* gbase, int K, char* lbase,
                                            int wave, int lane) {
#pragma unroll
  for (int i = 0; i < 4; ++i) {
    const int q = wave * 64 + lane + i * 256;
    const int r = q >> 3, c = (q & 7) ^ (r & 7);
    gl_lds16(gbase + (size_t)r * K + c * 8, lbase + i * 4096 + wave * 1024);
  }
}

// ---- BK=32 tiles ([rows][32], ((row>>1)&3) chunk-XOR swizzle; 2-way = free) -
__device__ __forceinline__ bf16x8 frag32(const u16* base, int row, int kchunk) {
  const int c = kchunk ^ ((row >> 1) & 3);
  return *(const bf16x8*)(base + row * 32 + c * 8);
}

// ---------------- merged cast fp32 -> bf16 (x, w_qkv, w_out in one launch) ---
__global__ __launch_bounds__(256) void castk3(const float* __restrict__ x,
                                              const float* __restrict__ wq,
                                              const float* __restrict__ wo,
                                              u16* __restrict__ xb,
                                              u16* __restrict__ wqb,
                                              u16* __restrict__ wob) {
  const int blk = blockIdx.x;
  const float* in;
  u16* out;
  int base;
  if (blk < 4096)      { in = x;  out = xb;  base = blk; }
  else if (blk < 5632) { in = wq; out = wqb; base = blk - 4096; }
  else                 { in = wo; out = wob; base = blk - 5632; }
  const int i = (base * 256 + threadIdx.x) * 8;
  float4 a = *(const float4*)(in + i);
  float4 b = *(const float4*)(in + i + 4);
  u16x8 v;
  v[0] = f2b(a.x); v[1] = f2b(a.y); v[2] = f2b(a.z); v[3] = f2b(a.w);
  v[4] = f2b(b.x); v[5] = f2b(b.y); v[6] = f2b(b.z); v[7] = f2b(b.w);
  *(u16x8*)(out + i) = v;
}

// ---------------- GEMM1: 256x128 tile, 256 thr, BK=32, dbuf (FROZEN) ---------
__global__ __launch_bounds__(256, 3) void gemm_qkv(
    const u16* __restrict__ A, const u16* __restrict__ B,
    u16* __restrict__ Qo, u16* __restrict__ Ko, u16* __restrict__ Vo) {
  __shared__ u16 As[2][256 * 32];   // 16KB per buf
  __shared__ u16 Bs[2][128 * 32];   // 8KB per buf
  const int tid = threadIdx.x;
  const int lane = tid & 63, wave = tid >> 6;
  const int fr = lane & 15, fg = lane >> 4;
  const int wm = wave >> 1, wn = wave & 1;
  const int bid = blockIdx.x;
  const int bm = bid & 31, bn = bid >> 5;   // 32 x 24 grid
  const int K = 1024;
  const u16* Ab = A + (size_t)bm * 256 * K;
  const u16* Bb = B + (size_t)bn * 128 * K;

  f32x4 acc[8][4] = {};

  auto stageA = [&](const u16* gbase, char* lbase) {
#pragma unroll
    for (int i = 0; i < 4; ++i) {
      const int q = wave * 64 + lane + i * 256;
      const int r = q >> 2, c = (q & 3) ^ ((r >> 1) & 3);
      gl_lds16(gbase + (size_t)r * K + c * 8, lbase + i * 4096 + wave * 1024);
    }
  };
  auto stageB = [&](const u16* gbase, char* lbase) {
#pragma unroll
    for (int i = 0; i < 2; ++i) {
      const int q = wave * 64 + lane + i * 256;
      const int r = q >> 2, c = (q & 3) ^ ((r >> 1) & 3);
      gl_lds16(gbase + (size_t)r * K + c * 8, lbase + i * 4096 + wave * 1024);
    }
  };

  stageA(Ab, (char*)&As[0][0]);
  stageB(Bb, (char*)&Bs[0][0]);
  __syncthreads();

  int cur = 0;
#pragma unroll 1
  for (int t = 0; t < 32; ++t) {
    if (t < 31) {
      stageA(Ab + (size_t)(t + 1) * 32, (char*)&As[cur ^ 1][0]);
      stageB(Bb + (size_t)(t + 1) * 32, (char*)&Bs[cur ^ 1][0]);
    }
    bf16x8 bfv[4];
#pragma unroll
    for (int ni = 0; ni < 4; ++ni)
      bfv[ni] = frag32(&Bs[cur][0], wn * 64 + ni * 16 + fr, fg);
#pragma unroll
    for (int mi = 0; mi < 8; ++mi) {
      const bf16x8 af = frag32(&As[cur][0], wm * 128 + mi * 16 + fr, fg);
#pragma unroll
      for (int ni = 0; ni < 4; ++ni)
        acc[mi][ni] = __builtin_amdgcn_mfma_f32_16x16x32_bf16(
            af, bfv[ni], acc[mi][ni], 0, 0, 0);
    }
    __syncthreads();
    cur ^= 1;
  }

  const int gr0 = bm * 256 + wm * 128;
  const int gc0 = bn * 128 + wn * 64;
#pragma unroll
  for (int mi = 0; mi < 8; ++mi) {
    const int rb = gr0 + mi * 16 + fg * 4;
    const int b = rb >> 10, t = rb & 1023;
#pragma unroll
    for (int ni = 0; ni < 4; ++ni) {
      const int c = gc0 + ni * 16 + fr;
      const int region = c >> 10, cc = c & 1023;
      const int h = cc >> 6, d = cc & 63;
      const size_t bh = (size_t)(b * 16 + h);
      if (region == 0) {
#pragma unroll
        for (int g = 0; g < 4; ++g)
          Qo[(bh * 1024 + t + g) * 64 + d] = f2b(acc[mi][ni][g] * QSCALE);
      } else if (region == 1) {
#pragma unroll
        for (int g = 0; g < 4; ++g)
          Ko[(bh * 1024 + t + g) * 64 + d] = f2b(acc[mi][ni][g]);
      } else {
        ushort4 pv;
        pv.x = f2b(acc[mi][ni][0]);
        pv.y = f2b(acc[mi][ni][1]);
        pv.z = f2b(acc[mi][ni][2]);
        pv.w = f2b(acc[mi][ni][3]);
        *(ushort4*)(Vo + (bh * 64 + d) * 1024 + t) = pv;   // V^T: [bh][d][t]
      }
    }
  }
}

// ---------------- GEMM2: 128x128, BK=64, dbuf, 1 sync/iter, swizzled --------
__global__ __launch_bounds__(256) void gemm_bt2(
    const u16* __restrict__ A, const u16* __restrict__ B,
    float* __restrict__ Co, const float* __restrict__ bias,
    const float* __restrict__ msk) {
  __shared__ u16 As[2][128 * 64];
  __shared__ u16 Bs[2][128 * 64];
  const int tid = threadIdx.x;
  const int lane = tid & 63, wave = tid >> 6;
  const int fr = lane & 15, fg = lane >> 4;
  const int wr = wave >> 1, wc = wave & 1;
  const int bid = blockIdx.x;
  const int bm = bid & 63, bn = bid >> 6;
  const int K = 1024, N = 1024;
  const u16* Ab = A + (size_t)bm * 128 * K;
  const u16* Bb = B + (size_t)bn * 128 * K;

  f32x4 acc[4][4] = {};

  stage_tile4(Ab, K, (char*)&As[0][0], wave, lane);
  stage_tile4(Bb, K, (char*)&Bs[0][0], wave, lane);
  __syncthreads();

  int cur = 0;
#pragma unroll 1
  for (int t = 0; t < 16; ++t) {
    if (t < 15) {
      stage_tile4(Ab + (size_t)(t + 1) * 64, K, (char*)&As[cur ^ 1][0], wave, lane);
      stage_tile4(Bb + (size_t)(t + 1) * 64, K, (char*)&Bs[cur ^ 1][0], wave, lane);
    }
    bf16x8 af[4][2], bfv[4][2];
#pragma unroll
    for (int mi = 0; mi < 4; ++mi)
#pragma unroll
      for (int kk = 0; kk < 2; ++kk)
        af[mi][kk] = frag(&As[cur][0], wr * 64 + mi * 16 + fr, kk * 4 + fg);
#pragma unroll
    for (int ni = 0; ni < 4; ++ni)
#pragma unroll
      for (int kk = 0; kk < 2; ++kk)
        bfv[ni][kk] = frag(&Bs[cur][0], wc * 64 + ni * 16 + fr, kk * 4 + fg);
#pragma unroll
    for (int mi = 0; mi < 4; ++mi)
#pragma unroll
      for (int ni = 0; ni < 4; ++ni)
#pragma unroll
        for (int kk = 0; kk < 2; ++kk)
          acc[mi][ni] = __builtin_amdgcn_mfma_f32_16x16x32_bf16(
              af[mi][kk], bfv[ni][kk], acc[mi][ni], 0, 0, 0);
    __syncthreads();
    cur ^= 1;
  }

  const int gr0 = bm * 128 + wr * 64;
  const int gc0 = bn * 128 + wc * 64;
#pragma unroll
  for (int mi = 0; mi < 4; ++mi) {
    const int rb = gr0 + mi * 16 + fg * 4;
#pragma unroll
    for (int ni = 0; ni < 4; ++ni) {
      const int c = gc0 + ni * 16 + fr;
      const float bo = bias[c];
#pragma unroll
      for (int g = 0; g < 4; ++g) {
        const int r = rb + g;
        Co[(size_t)r * N + c] = (acc[mi][ni][g] + bo) * msk[r];
      }
    }
  }
}

// ---------------- causal flash attention: 64-row strips, staged K/V ---------
// (r18 exact: mask row in LDS + allone flag; r19's "LDS diet" regressed 12us —
//  grid 1024 = 4 blocks/CU is the binding constraint, not LDS.)
__global__ __launch_bounds__(256) void attnk(const u16* __restrict__ Qb,
                                             const u16* __restrict__ Kb,
                                             const u16* __restrict__ Vtb,
                                             const float* __restrict__ msk,
                                             u16* __restrict__ Ob) {
  __shared__ u16 Ks[2][64 * 64];     // [buf][t][d], swizzled via staged source
  __shared__ u16 Vs[2][64 * 64];     // [buf][d][t], swizzled via staged source
  __shared__ float mlds[1024];       // padding mask row for this b
  __shared__ int allone;
  const int tid = threadIdx.x;
  const int lane = tid & 63, wave = tid >> 6;
  const int fr = lane & 15, fg = lane >> 4;
  const int bid = blockIdx.x;
  const int s = bid >> 7;            // pair index 0..7
  const int bh = bid & 127;
  const int b = bh >> 4, h = bh & 15;

  // preload padding mask row; detect trivial (all-ones) mask
  const float4 mv = ((const float4*)(msk + (size_t)b * 1024))[tid];
  ((float4*)mlds)[tid] = mv;
  if (tid == 0) allone = 1;
  __syncthreads();
  if (mv.x != 1.f || mv.y != 1.f || mv.z != 1.f || mv.w != 1.f) allone = 0;

  auto stage = [&](int kb, int buf) {
    const int q0 = wave * 64 + lane;
    const int r0 = q0 >> 3, c0 = (q0 & 7) ^ (r0 & 7);
    gl_lds16(Kb + ((size_t)bh * 1024 + kb * 64 + r0) * 64 + c0 * 8,
             (char*)&Ks[buf][0] + wave * 1024);
    gl_lds16(Vtb + ((size_t)bh * 64 + r0) * 1024 + kb * 64 + c0 * 8,
             (char*)&Vs[buf][0] + wave * 1024);
    const int q1 = q0 + 256;
    const int r1 = q1 >> 3, c1 = (q1 & 7) ^ (r1 & 7);
    gl_lds16(Kb + ((size_t)bh * 1024 + kb * 64 + r1) * 64 + c1 * 8,
             (char*)&Ks[buf][0] + 4096 + wave * 1024);
    gl_lds16(Vtb + ((size_t)bh * 64 + r1) * 1024 + kb * 64 + c1 * 8,
             (char*)&Vs[buf][0] + 4096 + wave * 1024);
  };

  int qw = s * 64 + wave * 16;       // wave's 16 q-rows
  bf16x8 qf[2];
  auto loadQ = [&]() {
#pragma unroll
    for (int kc = 0; kc < 2; ++kc)
      qf[kc] = *(const bf16x8*)(Qb + ((size_t)bh * 1024 + qw + fr) * 64 +
                                kc * 32 + fg * 8);
  };
  loadQ();

  f32x4 o[4] = {};
  float mrun = -3.0e38f, lrun = 0.f;

  auto writeO = [&]() {
    const float inv = 1.0f / lrun;
#pragma unroll
    for (int g = 0; g < 4; ++g) {
      const float invr = __shfl(inv, fg * 4 + g);
      const int q = qw + fg * 4 + g;
#pragma unroll
      for (int dt = 0; dt < 4; ++dt)
        Ob[((size_t)b * 1024 + q) * 1024 + h * 64 + dt * 16 + fr] =
            f2b(o[dt][g] * invr);
    }
  };

  stage(0, 0);   // prologue: strip A, kb=0

#pragma unroll 1
  for (int it = 0; it <= 16; ++it) {   // 17 subs, uniform for every block
    __syncthreads();                   // stage(it) landed; allone settled
    const bool mfast = __builtin_amdgcn_readfirstlane(allone) != 0;
    if (it < 16) {                     // prefetch next sub; hides under compute
      const int nkb = (it + 1 <= s) ? (it + 1) : (it - s);
      stage(nkb, (it + 1) & 1);
    }
    if (it == s + 1) {                 // switch strip A -> strip B
      writeO();
      qw = (15 - s) * 64 + wave * 16;
      loadQ();
#pragma unroll
      for (int dt = 0; dt < 4; ++dt) o[dt] = f32x4{0.f, 0.f, 0.f, 0.f};
      mrun = -3.0e38f;
      lrun = 0.f;
    }
    const int kb = (it <= s) ? it : (it - s - 1);
    const u16* Kc = &Ks[it & 1][0];
    const u16* Vc = &Vs[it & 1][0];

    // --- S^T = K * Q^T : lane owns q-row = qw+fr, k = nt*16 + fg*4 + g ---
    f32x4 st[4];
    const f32x4 z = {0.f, 0.f, 0.f, 0.f};
    bf16x8 kf0[4], kf1[4];
#pragma unroll
    for (int nt = 0; nt < 4; ++nt) {
      const int krow = nt * 16 + fr;
      const int cb0r = (0 * 4 + fg) ^ (krow & 7);
      const int cb1r = (1 * 4 + fg) ^ (krow & 7);
      kf0[nt] = *(const bf16x8*)(Kc + krow * 64 + cb0r * 8);
      kf1[nt] = *(const bf16x8*)(Kc + krow * 64 + cb1r * 8);
    }
    __builtin_amdgcn_s_setprio(1);
#pragma unroll
    for (int nt = 0; nt < 4; ++nt) {
      st[nt] = __builtin_amdgcn_mfma_f32_16x16x32_bf16(kf0[nt], qf[0], z, 0, 0, 0);
      st[nt] = __builtin_amdgcn_mfma_f32_16x16x32_bf16(kf1[nt], qf[1], st[nt], 0, 0, 0);
    }
    __builtin_amdgcn_s_setprio(0);

    // --- causal mask: needed unless ALL keys <= MIN q-row of the wave (qw) ---
    if (kb * 64 + 63 > qw) {
      const int q = qw + fr;
#pragma unroll
      for (int nt = 0; nt < 4; ++nt)
#pragma unroll
        for (int g = 0; g < 4; ++g) {
          const int j = kb * 64 + nt * 16 + fg * 4 + g;
          if (j > q) st[nt][g] = -3.0e38f;
        }
    }

    // --- online softmax with defer-max (T13, THR=8) ---
    float mxl = st[0][0];
#pragma unroll
    for (int nt = 0; nt < 4; ++nt)
#pragma unroll
      for (int g = 0; g < 4; ++g) mxl = fmaxf(mxl, st[nt][g]);
    float nm, sc;
    int doR;
    if (__all(mxl <= mrun + 8.f)) {
      nm = mrun; sc = 1.f; doR = 0;
    } else {
      float mx = fmaxf(mxl, __shfl_xor(mxl, 16));
      mx = fmaxf(mx, __shfl_xor(mx, 32));
      nm = fmaxf(mrun, mx);
      sc = exp2f(mrun - nm);
      mrun = nm; doR = 1;
    }
    float rs = 0.f;
    if (mfast) {                       // trivial padding mask: skip loads+mults
#pragma unroll
      for (int nt = 0; nt < 4; ++nt)
#pragma unroll
        for (int g = 0; g < 4; ++g) {
          const float pq = exp2f(st[nt][g] - nm);
          st[nt][g] = pq;
          rs += pq;
        }
    } else {
      float kmv[4][4];
#pragma unroll
      for (int nt = 0; nt < 4; ++nt) {
        const float4 km4 = *(const float4*)(&mlds[kb * 64 + nt * 16 + fg * 4]);
        kmv[nt][0] = km4.x; kmv[nt][1] = km4.y; kmv[nt][2] = km4.z; kmv[nt][3] = km4.w;
      }
#pragma unroll
      for (int nt = 0; nt < 4; ++nt)
#pragma unroll
        for (int g = 0; g < 4; ++g) {
          const float pq = exp2f(st[nt][g] - nm) * kmv[nt][g];
          st[nt][g] = pq;
          rs += pq;
        }
    }
    rs += __shfl_xor(rs, 16);
    rs += __shfl_xor(rs, 32);
    lrun = doR ? (lrun * sc + rs) : (lrun + rs);

    // --- pack P pairs to bf16x2 words (v_cvt_pk_bf16_f32) ---
    int pk[4][2];
#pragma unroll
    for (int nt = 0; nt < 4; ++nt)
#pragma unroll
      for (int hh = 0; hh < 2; ++hh) {
        bf16x2 tp;
        tp[0] = (bf16)st[nt][2 * hh];
        tp[1] = (bf16)st[nt][2 * hh + 1];
        pk[nt][hh] = __builtin_bit_cast(int, tp);
      }

    // --- redistribute to PV A-fragments via shfl (wave-uniform reg indices,
    //     per-lane select; lane-varying index inside __shfl was the r8 bug) ---
    bf16x8 pa[2];
#pragma unroll
    for (int jc = 0; jc < 2; ++jc) {
      int w[4];
#pragma unroll
      for (int e2 = 0; e2 < 4; ++e2) {
        const int sl = fr + ((fg & 1) << 5) + ((e2 & 2) ? 16 : 0);
        const int lo = __shfl(pk[jc * 2 + 0][e2 & 1], sl);
        const int hi = __shfl(pk[jc * 2 + 1][e2 & 1], sl);
        w[e2] = (fg & 2) ? hi : lo;
      }
      int4 wi = {w[0], w[1], w[2], w[3]};
      pa[jc] = __builtin_bit_cast(bf16x8, wi);
    }

    // --- rescale O only when max grew (wave-uniform branch) ---
    if (doR) {
#pragma unroll
      for (int g = 0; g < 4; ++g) {
        const float scr = __shfl(sc, fg * 4 + g);
#pragma unroll
        for (int dt = 0; dt < 4; ++dt) o[dt][g] *= scr;
      }
    }

    // --- PV: O[q][d] += P[q][k] * V[k][d] ---
    __builtin_amdgcn_s_setprio(1);
#pragma unroll
    for (int jc = 0; jc < 2; ++jc)
#pragma unroll
      for (int dt = 0; dt < 4; ++dt) {
        const int vrow = dt * 16 + fr;
        const int cb = (jc * 4 + fg) ^ (vrow & 7);
        const bf16x8 vf = *(const bf16x8*)(Vc + vrow * 64 + cb * 8);
        o[dt] = __builtin_amdgcn_mfma_f32_16x16x32_bf16(pa[jc], vf, o[dt], 0, 0, 0);
      }
    __builtin_amdgcn_s_setprio(0);
  }

  writeO();   // strip B epilogue
}

// ---------------- launcher ----------------
extern "C" void kernel_launch(void* const* d_in, const int* in_sizes, int n_in,
                              void* d_out, int out_size, void* d_ws, size_t ws_size,
                              hipStream_t stream) {
  (void)in_sizes; (void)n_in; (void)out_size; (void)ws_size;
  const float* x = (const float*)d_in[0];
  const float* m = (const float*)d_in[1];
  const float* w_qkv = (const float*)d_in[2];
  const float* w_out = (const float*)d_in[3];
  const float* b_out = (const float*)d_in[4];
  float* out = (float*)d_out;

  char* ws = (char*)d_ws;
  const size_t MB = 1u << 20;
  u16* Xb    = (u16*)(ws + 0);         // 16MB, reused as Ob after GEMM1
  u16* Wqkvb = (u16*)(ws + 16 * MB);   // 6MB
  u16* Woutb = (u16*)(ws + 22 * MB);   // 2MB
  u16* Qb    = (u16*)(ws + 24 * MB);   // 16MB
  u16* Kb    = (u16*)(ws + 40 * MB);   // 16MB
  u16* Vtb   = (u16*)(ws + 56 * MB);   // 16MB  -> total 72MB
  u16* Ob    = Xb;                      // alias: X dead after GEMM1

  // merged casts (one launch: x, w_qkv, w_out)
  castk3<<<6144, 256, 0, stream>>>(x, w_qkv, w_out, Xb, Wqkvb, Woutb);

  // GEMM1: qkv = X @ Wqkv^T (256x128 tile, 256 thr, BK=32 dbuf, 3 blocks/CU)
  gemm_qkv<<<768, 256, 0, stream>>>(Xb, Wqkvb, Qb, Kb, Vtb);

  // flash attention (64-row strips paired, staged K/V, mask fast-path in LDS)
  attnk<<<1024, 256, 0, stream>>>(Qb, Kb, Vtb, m, Ob);

  // GEMM2: out = (O @ Wout^T + b_out) * m  (128^2, BK=64 dbuf)
  gemm_bt2<<<512, 256, 0, stream>>>(Ob, Woutb, out, b_out, m);
}